// Round 1
// baseline (1033.061 us; speedup 1.0000x reference)
//
#include <hip/hip_runtime.h>
#include <hip/hip_bf16.h>
#include <cstdint>

#define B_ 2
#define S_ 2048
#define HID_ 2560
#define H_ 40
#define NOPE_ 64
#define ROPE_ 32
#define VD_ 64
#define QKD_ 96
#define QRANK_ 768
#define KVRANK_ 256
#define KVRP_ 288
#define KVRP_PAD 384
#define HQKD (H_*QKD_)          // 3840
#define HKV  (H_*(NOPE_+VD_))   // 5120
#define HVD  (H_*VD_)           // 2560
#define TOK  (B_*S_)            // 4096
#define EPS_ 1e-5f
#define SCALING_ 0.10206207261596575f

typedef __bf16  bf16x8  __attribute__((ext_vector_type(8)));
typedef float   floatx4 __attribute__((ext_vector_type(4)));
typedef short   shortx4 __attribute__((ext_vector_type(4)));
typedef unsigned short ushort8_t __attribute__((ext_vector_type(8)));

__device__ __forceinline__ unsigned short f2bf(float f) {
    unsigned int u = __builtin_bit_cast(unsigned int, f);
    unsigned int r = (u + 0x7FFFu + ((u >> 16) & 1u)) >> 16;  // RNE
    return (unsigned short)r;
}
__device__ __forceinline__ float bf2f(unsigned short h) {
    return __builtin_bit_cast(float, ((unsigned int)h) << 16);
}
// read element i of an input buffer that is either f32 (bf=0) or bf16 (bf=1)
__device__ __forceinline__ float load_in(const void* p, long i, int bf) {
    if (bf) return bf2f(((const unsigned short*)p)[i]);
    return ((const float*)p)[i];
}

// ---- dtype detector: cos[0]==1.0 -> f32 stores 0x0000 in first half-word,
// bf16 stores 0x3F80.
__global__ void k_detect(const unsigned short* cosb, int* flag) {
    if (threadIdx.x == 0) flag[0] = (cosb[0] != 0) ? 1 : 0;
}

// ---- elementwise convert input -> bf16 buffer
__global__ void k_tobf(const void* in, unsigned short* out, long n, const int* flag) {
    int bf = flag[0];
    long i = (long)blockIdx.x * blockDim.x + threadIdx.x;
    if (i >= n) return;
    out[i] = bf ? ((const unsigned short*)in)[i] : f2bf(((const float*)in)[i]);
}

// ---- LDS-tiled transpose+cast: in [K][N] (f32 or bf16) -> out bf16 [Npad][K], zero-fill n>=N
__global__ __launch_bounds__(256) void k_transpose(const void* in, unsigned short* out,
                                                   int K, int N, int Npad, const int* flag) {
    __shared__ float tile[32][33];
    int bf = flag[0];
    int k0 = blockIdx.x * 32;
    int n0 = blockIdx.y * 32;
    int tx = threadIdx.x & 31, ty = threadIdx.x >> 5;
#pragma unroll
    for (int i = 0; i < 4; i++) {
        int k = k0 + ty + 8 * i, n = n0 + tx;
        float v = 0.f;
        if (n < N && k < K) v = load_in(in, (long)k * N + n, bf);
        tile[ty + 8 * i][tx] = v;
    }
    __syncthreads();
#pragma unroll
    for (int i = 0; i < 4; i++) {
        int n = n0 + ty + 8 * i, k = k0 + tx;
        if (n < Npad && k < K) out[(long)n * K + k] = f2bf(tile[tx][ty + 8 * i]);
    }
}

// ---- RMSNorm: in f32 [rows][ldin], first L cols; out bf16 [rows][ldout]
__global__ __launch_bounds__(256) void k_rmsnorm(const float* in, int ldin, int L,
                                                 const void* w, unsigned short* out,
                                                 int ldout, const int* flag) {
    int bf = flag[0];
    long row = blockIdx.x;
    const float* x = in + row * ldin;
    float ss = 0.f;
    for (int i = threadIdx.x; i < L; i += 256) { float v = x[i]; ss += v * v; }
    __shared__ float red[256];
    red[threadIdx.x] = ss;
    __syncthreads();
    for (int s = 128; s > 0; s >>= 1) {
        if (threadIdx.x < s) red[threadIdx.x] += red[threadIdx.x + s];
        __syncthreads();
    }
    float scale = rsqrtf(red[0] / (float)L + EPS_);
    for (int i = threadIdx.x; i < L; i += 256)
        out[row * ldout + i] = f2bf(x[i] * scale * load_in(w, i, bf));
}

// ---- RoPE on q (in-place, bf16): dims [NOPE, NOPE+32) of each head
__global__ void k_rope_q(unsigned short* q, const void* cosb, const void* sinb, const int* flag) {
    int bf = flag[0];
    long i = (long)blockIdx.x * blockDim.x + threadIdx.x;  // TOK*H*16
    if (i >= (long)TOK * H_ * 16) return;
    int r = (int)(i & 15);
    long t = i >> 4;
    int h = (int)(t % H_);
    long tok = t / H_;
    int s = (int)(tok % S_);
    long base = tok * HQKD + h * QKD_ + NOPE_;
    float x1 = bf2f(q[base + r]), x2 = bf2f(q[base + 16 + r]);
    float c1 = load_in(cosb, (long)s * ROPE_ + r, bf);
    float s1 = load_in(sinb, (long)s * ROPE_ + r, bf);
    float c2 = load_in(cosb, (long)s * ROPE_ + 16 + r, bf);
    float s2 = load_in(sinb, (long)s * ROPE_ + 16 + r, bf);
    q[base + r]      = f2bf(x1 * c1 - x2 * s1);
    q[base + 16 + r] = f2bf(x2 * c2 + x1 * s2);
}

// ---- RoPE on shared k_rot: ckv f32 cols [256,288) -> krot bf16 [TOK][32]
__global__ void k_rope_k(const float* ckv, unsigned short* krot,
                         const void* cosb, const void* sinb, const int* flag) {
    int bf = flag[0];
    long i = (long)blockIdx.x * blockDim.x + threadIdx.x;  // TOK*16
    if (i >= (long)TOK * 16) return;
    int r = (int)(i & 15);
    long tok = i >> 4;
    int s = (int)(tok % S_);
    const float* x = ckv + tok * KVRP_PAD + KVRANK_;
    float x1 = x[r], x2 = x[16 + r];
    float c1 = load_in(cosb, (long)s * ROPE_ + r, bf);
    float s1 = load_in(sinb, (long)s * ROPE_ + r, bf);
    float c2 = load_in(cosb, (long)s * ROPE_ + 16 + r, bf);
    float s2 = load_in(sinb, (long)s * ROPE_ + 16 + r, bf);
    krot[tok * ROPE_ + r]      = f2bf(x1 * c1 - x2 * s1);
    krot[tok * ROPE_ + 16 + r] = f2bf(x2 * c2 + x1 * s2);
}

// ---- bf16 MFMA GEMM: C[M][N] = A[M][K] * B[K][N], A bf16 row-major,
// Bt = B^T bf16 [N][K]. 128x128 tile, BK=32, 4 waves (2x2), 4x4 mfma each.
// out_mode: 0 = f32 C, 1 = bf16 C, 2 = per flag
__global__ __launch_bounds__(256) void k_gemm(const unsigned short* A, const unsigned short* Bt,
                                              void* C, int M, int N, int K,
                                              int out_mode, const int* flag) {
    int obf = (out_mode == 2) ? flag[0] : out_mode;
    __shared__ __align__(16) unsigned short As[128][40];
    __shared__ __align__(16) unsigned short Bs[128][40];
    int tid = threadIdx.x;
    int gm = blockIdx.y * 128, gn = blockIdx.x * 128;
    int lane = tid & 63, w = tid >> 6, wm = w >> 1, wn = w & 1;
    int g = lane >> 4, qi = lane & 15;
    floatx4 acc[4][4];
#pragma unroll
    for (int mt = 0; mt < 4; mt++)
#pragma unroll
        for (int nt = 0; nt < 4; nt++) acc[mt][nt] = (floatx4){0.f, 0.f, 0.f, 0.f};

    for (int k0 = 0; k0 < K; k0 += 32) {
        __syncthreads();
#pragma unroll
        for (int i = 0; i < 2; i++) {
            int c = tid + i * 256;
            int row = c >> 2, kc = (c & 3) * 8;
            *(ushort8_t*)&As[row][kc] = *(const ushort8_t*)&A[(long)(gm + row) * K + k0 + kc];
            *(ushort8_t*)&Bs[row][kc] = *(const ushort8_t*)&Bt[(long)(gn + row) * K + k0 + kc];
        }
        __syncthreads();
        bf16x8 fa[4], fb[4];
#pragma unroll
        for (int mt = 0; mt < 4; mt++) fa[mt] = *(const bf16x8*)&As[wm * 64 + mt * 16 + qi][g * 8];
#pragma unroll
        for (int nt = 0; nt < 4; nt++) fb[nt] = *(const bf16x8*)&Bs[wn * 64 + nt * 16 + qi][g * 8];
#pragma unroll
        for (int mt = 0; mt < 4; mt++)
#pragma unroll
            for (int nt = 0; nt < 4; nt++)
                acc[mt][nt] = __builtin_amdgcn_mfma_f32_16x16x32_bf16(fa[mt], fb[nt], acc[mt][nt], 0, 0, 0);
    }
#pragma unroll
    for (int mt = 0; mt < 4; mt++)
#pragma unroll
        for (int nt = 0; nt < 4; nt++)
#pragma unroll
            for (int r = 0; r < 4; r++) {
                long row = gm + wm * 64 + mt * 16 + g * 4 + r;
                long col = gn + wn * 64 + nt * 16 + qi;
                float v = acc[mt][nt][r];
                if (obf) ((unsigned short*)C)[row * N + col] = f2bf(v);
                else     ((float*)C)[row * N + col] = v;
            }
}

// ---- flash attention: one wave per (b,h,16-row q tile).
// Computes S^T = K*Q^T so P exits in PV A-operand layout directly.
__global__ __launch_bounds__(256) void k_attn(const unsigned short* q, const unsigned short* kv,
                                              const unsigned short* krot, unsigned short* out) {
    int lane = threadIdx.x & 63, w = threadIdx.x >> 6;
    int b = blockIdx.z, h = blockIdx.y;
    int qt = blockIdx.x * 4 + w;
    int g = lane >> 4, qi = lane & 15;
    long tok0 = (long)b * S_;
    int qrow = qt * 16 + qi;

    const unsigned short* qp = q + (tok0 + qrow) * HQKD + h * QKD_;
    bf16x8 fq[3];
#pragma unroll
    for (int c = 0; c < 3; c++) fq[c] = *(const bf16x8*)&qp[c * 32 + g * 8];

    floatx4 o[4];
#pragma unroll
    for (int vc = 0; vc < 4; vc++) o[vc] = (floatx4){0.f, 0.f, 0.f, 0.f};
    float m = -1e30f, lsum = 0.f;

    for (int kt = 0; kt <= qt; kt++) {
        long krow = tok0 + (long)kt * 16;
        const unsigned short* kp = kv + (krow + qi) * HKV + h * (NOPE_ + VD_);
        bf16x8 fk0 = *(const bf16x8*)&kp[g * 8];
        bf16x8 fk1 = *(const bf16x8*)&kp[32 + g * 8];
        bf16x8 fk2 = *(const bf16x8*)&krot[(krow + qi) * ROPE_ + g * 8];
        floatx4 st = (floatx4){0.f, 0.f, 0.f, 0.f};
        st = __builtin_amdgcn_mfma_f32_16x16x32_bf16(fk0, fq[0], st, 0, 0, 0);
        st = __builtin_amdgcn_mfma_f32_16x16x32_bf16(fk1, fq[1], st, 0, 0, 0);
        st = __builtin_amdgcn_mfma_f32_16x16x32_bf16(fk2, fq[2], st, 0, 0, 0);
        // st[r] = S^T[ktok = kt*16+g*4+r][q = qt*16+qi]
        float sv[4], tmax = -3e30f;
#pragma unroll
        for (int r = 0; r < 4; r++) {
            float s = st[r] * SCALING_;
            if (kt == qt && (kt * 16 + g * 4 + r) > qrow) s = -1e30f;
            sv[r] = s;
            tmax = fmaxf(tmax, s);
        }
        tmax = fmaxf(tmax, __shfl_xor(tmax, 16, 64));
        tmax = fmaxf(tmax, __shfl_xor(tmax, 32, 64));
        float mnew = fmaxf(m, tmax);
        float alpha = __expf(m - mnew);
        float ps = 0.f;
        shortx4 fp;
#pragma unroll
        for (int r = 0; r < 4; r++) {
            float p = __expf(sv[r] - mnew);
            ps += p;
            fp[r] = (short)f2bf(p);
        }
        ps += __shfl_xor(ps, 16, 64);
        ps += __shfl_xor(ps, 32, 64);
        lsum = lsum * alpha + ps;
        m = mnew;
        float ar[4];
#pragma unroll
        for (int r = 0; r < 4; r++) ar[r] = __shfl(alpha, (lane & 48) | (g * 4 + r), 64);
#pragma unroll
        for (int vc = 0; vc < 4; vc++) {
            o[vc][0] *= ar[0]; o[vc][1] *= ar[1]; o[vc][2] *= ar[2]; o[vc][3] *= ar[3];
        }
        const unsigned short* vp = kv + krow * HKV + h * (NOPE_ + VD_) + NOPE_;
#pragma unroll
        for (int vc = 0; vc < 4; vc++) {
            shortx4 fv;
#pragma unroll
            for (int j = 0; j < 4; j++)
                fv[j] = (short)vp[(long)(g * 4 + j) * HKV + vc * 16 + qi];
            o[vc] = __builtin_amdgcn_mfma_f32_16x16x16bf16_1k(fp, fv, o[vc], 0, 0, 0);
        }
    }
    float lr[4];
#pragma unroll
    for (int r = 0; r < 4; r++) lr[r] = __shfl(lsum, (lane & 48) | (g * 4 + r), 64);
#pragma unroll
    for (int vc = 0; vc < 4; vc++)
#pragma unroll
        for (int r = 0; r < 4; r++)
            out[(tok0 + qt * 16 + g * 4 + r) * HVD + h * VD_ + vc * 16 + qi] =
                f2bf(o[vc][r] / lr[r]);
}

extern "C" void kernel_launch(void* const* d_in, const int* in_sizes, int n_in,
                              void* d_out, int out_size, void* d_ws, size_t ws_size,
                              hipStream_t stream) {
    const void* hidden = d_in[0];
    const void* cosb   = d_in[1];
    const void* sinb   = d_in[2];
    const void* wq_a   = d_in[3];
    const void* q_ln   = d_in[4];
    const void* wq_b   = d_in[5];
    const void* wkv_a  = d_in[6];
    const void* kv_ln  = d_in[7];
    const void* wkv_b  = d_in[8];
    const void* wo     = d_in[9];

    char* ws = (char*)d_ws;
    size_t off = 0;
    auto alloc = [&](size_t bytes) -> void* {
        void* p = ws + off;
        off += (bytes + 255) & ~(size_t)255;
        return p;
    };
    int* flag                = (int*)alloc(256);
    unsigned short* hbf      = (unsigned short*)alloc((size_t)TOK * HID_ * 2);
    unsigned short* wqa_t    = (unsigned short*)alloc((size_t)QRANK_ * HID_ * 2);
    unsigned short* wqb_t    = (unsigned short*)alloc((size_t)HQKD * QRANK_ * 2);
    unsigned short* wkva_t   = (unsigned short*)alloc((size_t)KVRP_PAD * HID_ * 2);
    unsigned short* wkvb_t   = (unsigned short*)alloc((size_t)HKV * KVRANK_ * 2);
    unsigned short* wo_t     = (unsigned short*)alloc((size_t)HID_ * HVD * 2);
    float*          q_a      = (float*)alloc((size_t)TOK * QRANK_ * 4);
    unsigned short* q_a_n    = (unsigned short*)alloc((size_t)TOK * QRANK_ * 2);
    unsigned short* q_raw    = (unsigned short*)alloc((size_t)TOK * HQKD * 2);
    float*          ckv      = (float*)alloc((size_t)TOK * KVRP_PAD * 4);
    unsigned short* kc_n     = (unsigned short*)alloc((size_t)TOK * KVRANK_ * 2);
    unsigned short* kv_raw   = (unsigned short*)alloc((size_t)TOK * HKV * 2);
    unsigned short* krot     = (unsigned short*)alloc((size_t)TOK * ROPE_ * 2);
    unsigned short* attn_o   = (unsigned short*)alloc((size_t)TOK * HVD * 2);

    k_detect<<<1, 64, 0, stream>>>((const unsigned short*)cosb, flag);

    long nh = (long)TOK * HID_;
    k_tobf<<<(int)((nh + 255) / 256), 256, 0, stream>>>(hidden, hbf, nh, flag);

    k_transpose<<<dim3(HID_ / 32, QRANK_ / 32), 256, 0, stream>>>(wq_a, wqa_t, HID_, QRANK_, QRANK_, flag);
    k_transpose<<<dim3(QRANK_ / 32, HQKD / 32), 256, 0, stream>>>(wq_b, wqb_t, QRANK_, HQKD, HQKD, flag);
    k_transpose<<<dim3(HID_ / 32, KVRP_PAD / 32), 256, 0, stream>>>(wkv_a, wkva_t, HID_, KVRP_, KVRP_PAD, flag);
    k_transpose<<<dim3(KVRANK_ / 32, HKV / 32), 256, 0, stream>>>(wkv_b, wkvb_t, KVRANK_, HKV, HKV, flag);
    k_transpose<<<dim3(HVD / 32, HID_ / 32), 256, 0, stream>>>(wo, wo_t, HVD, HID_, HID_, flag);

    // q chain
    k_gemm<<<dim3(QRANK_ / 128, TOK / 128), 256, 0, stream>>>(hbf, wqa_t, q_a, TOK, QRANK_, HID_, 0, flag);
    k_rmsnorm<<<TOK, 256, 0, stream>>>(q_a, QRANK_, QRANK_, q_ln, q_a_n, QRANK_, flag);
    k_gemm<<<dim3(HQKD / 128, TOK / 128), 256, 0, stream>>>(q_a_n, wqb_t, q_raw, TOK, HQKD, QRANK_, 1, flag);

    // kv chain
    k_gemm<<<dim3(KVRP_PAD / 128, TOK / 128), 256, 0, stream>>>(hbf, wkva_t, ckv, TOK, KVRP_PAD, HID_, 0, flag);
    k_rmsnorm<<<TOK, 256, 0, stream>>>(ckv, KVRP_PAD, KVRANK_, kv_ln, kc_n, KVRANK_, flag);
    k_gemm<<<dim3(HKV / 128, TOK / 128), 256, 0, stream>>>(kc_n, wkvb_t, kv_raw, TOK, HKV, KVRANK_, 1, flag);

    // rope
    long nrq = (long)TOK * H_ * 16;
    k_rope_q<<<(int)((nrq + 255) / 256), 256, 0, stream>>>(q_raw, cosb, sinb, flag);
    long nrk = (long)TOK * 16;
    k_rope_k<<<(int)((nrk + 255) / 256), 256, 0, stream>>>(ckv, krot, cosb, sinb, flag);

    // attention
    k_attn<<<dim3(S_ / 64, H_, B_), 256, 0, stream>>>(q_raw, kv_raw, krot, attn_o);

    // output projection (dtype per detected mode)
    k_gemm<<<dim3(HID_ / 128, TOK / 128), 256, 0, stream>>>(attn_o, wo_t, d_out, TOK, HID_, HVD, 2, flag);
}

// Round 2
// 873.432 us; speedup vs baseline: 1.1828x; 1.1828x over previous
//
#include <hip/hip_runtime.h>
#include <hip/hip_bf16.h>
#include <cstdint>

#define B_ 2
#define S_ 2048
#define HID_ 2560
#define H_ 40
#define NOPE_ 64
#define ROPE_ 32
#define VD_ 64
#define QKD_ 96
#define QRANK_ 768
#define KVRANK_ 256
#define KVRP_ 288
#define KVRP_PAD 384
#define HQKD (H_*QKD_)          // 3840
#define HKV  (H_*(NOPE_+VD_))   // 5120
#define HVD  (H_*VD_)           // 2560
#define TOK  (B_*S_)            // 4096
#define EPS_ 1e-5f
#define SCALING_ 0.10206207261596575f

typedef __bf16  bf16x8  __attribute__((ext_vector_type(8)));
typedef float   floatx4 __attribute__((ext_vector_type(4)));
typedef short   shortx4 __attribute__((ext_vector_type(4)));
typedef unsigned short ushort8_t __attribute__((ext_vector_type(8)));

__device__ __forceinline__ unsigned short f2bf(float f) {
    unsigned int u = __builtin_bit_cast(unsigned int, f);
    unsigned int r = (u + 0x7FFFu + ((u >> 16) & 1u)) >> 16;  // RNE
    return (unsigned short)r;
}
__device__ __forceinline__ float bf2f(unsigned short h) {
    return __builtin_bit_cast(float, ((unsigned int)h) << 16);
}
__device__ __forceinline__ float load_in(const void* p, long i, int bf) {
    if (bf) return bf2f(((const unsigned short*)p)[i]);
    return ((const float*)p)[i];
}

// ---- dtype detector: cos[0]==1.0 -> f32 stores 0x0000 in first half-word,
// bf16 stores 0x3F80.
__global__ void k_detect(const unsigned short* cosb, int* flag) {
    if (threadIdx.x == 0) flag[0] = (cosb[0] != 0) ? 1 : 0;
}

__global__ void k_tobf(const void* in, unsigned short* out, long n, const int* flag) {
    int bf = flag[0];
    long i = (long)blockIdx.x * blockDim.x + threadIdx.x;
    if (i >= n) return;
    out[i] = bf ? ((const unsigned short*)in)[i] : f2bf(((const float*)in)[i]);
}

// ---- LDS-tiled transpose+cast: in [K][N] -> out bf16 [Npad][K], zero-fill n>=N
__global__ __launch_bounds__(256) void k_transpose(const void* in, unsigned short* out,
                                                   int K, int N, int Npad, const int* flag) {
    __shared__ float tile[32][33];
    int bf = flag[0];
    int k0 = blockIdx.x * 32;
    int n0 = blockIdx.y * 32;
    int tx = threadIdx.x & 31, ty = threadIdx.x >> 5;
#pragma unroll
    for (int i = 0; i < 4; i++) {
        int k = k0 + ty + 8 * i, n = n0 + tx;
        float v = 0.f;
        if (n < N && k < K) v = load_in(in, (long)k * N + n, bf);
        tile[ty + 8 * i][tx] = v;
    }
    __syncthreads();
#pragma unroll
    for (int i = 0; i < 4; i++) {
        int n = n0 + ty + 8 * i, k = k0 + tx;
        if (n < Npad && k < K) out[(long)n * K + k] = f2bf(tile[tx][ty + 8 * i]);
    }
}

// ---- transpose V out of kv_raw: [tok][h*128+64+vd] -> vt[(b*H+h)*64+vd][S]
__global__ __launch_bounds__(256) void k_vtrans(const unsigned short* kv, unsigned short* vt) {
    __shared__ unsigned short t[32][33];
    int bh = blockIdx.z;
    int s0 = blockIdx.x * 32, v0 = blockIdx.y * 32;
    int b = bh / H_, h = bh % H_;
    int tx = threadIdx.x & 31, ty = threadIdx.x >> 5;
#pragma unroll
    for (int i = 0; i < 4; i++) {
        int s = s0 + ty + 8 * i, vd = v0 + tx;
        t[ty + 8 * i][tx] = kv[((long)b * S_ + s) * HKV + h * 128 + 64 + vd];
    }
    __syncthreads();
#pragma unroll
    for (int i = 0; i < 4; i++) {
        int vd = v0 + ty + 8 * i, s = s0 + tx;
        vt[((long)bh * 64 + vd) * S_ + s] = t[tx][ty + 8 * i];
    }
}

// ---- RMSNorm
__global__ __launch_bounds__(256) void k_rmsnorm(const float* in, int ldin, int L,
                                                 const void* w, unsigned short* out,
                                                 int ldout, const int* flag) {
    int bf = flag[0];
    long row = blockIdx.x;
    const float* x = in + row * ldin;
    float ss = 0.f;
    for (int i = threadIdx.x; i < L; i += 256) { float v = x[i]; ss += v * v; }
    __shared__ float red[256];
    red[threadIdx.x] = ss;
    __syncthreads();
    for (int s = 128; s > 0; s >>= 1) {
        if (threadIdx.x < s) red[threadIdx.x] += red[threadIdx.x + s];
        __syncthreads();
    }
    float scale = rsqrtf(red[0] / (float)L + EPS_);
    for (int i = threadIdx.x; i < L; i += 256)
        out[row * ldout + i] = f2bf(x[i] * scale * load_in(w, i, bf));
}

// ---- RoPE on q (in-place, bf16)
__global__ void k_rope_q(unsigned short* q, const void* cosb, const void* sinb, const int* flag) {
    int bf = flag[0];
    long i = (long)blockIdx.x * blockDim.x + threadIdx.x;
    if (i >= (long)TOK * H_ * 16) return;
    int r = (int)(i & 15);
    long t = i >> 4;
    int h = (int)(t % H_);
    long tok = t / H_;
    int s = (int)(tok % S_);
    long base = tok * HQKD + h * QKD_ + NOPE_;
    float x1 = bf2f(q[base + r]), x2 = bf2f(q[base + 16 + r]);
    float c1 = load_in(cosb, (long)s * ROPE_ + r, bf);
    float s1 = load_in(sinb, (long)s * ROPE_ + r, bf);
    float c2 = load_in(cosb, (long)s * ROPE_ + 16 + r, bf);
    float s2 = load_in(sinb, (long)s * ROPE_ + 16 + r, bf);
    q[base + r]      = f2bf(x1 * c1 - x2 * s1);
    q[base + 16 + r] = f2bf(x2 * c2 + x1 * s2);
}

// ---- RoPE on shared k_rot
__global__ void k_rope_k(const float* ckv, unsigned short* krot,
                         const void* cosb, const void* sinb, const int* flag) {
    int bf = flag[0];
    long i = (long)blockIdx.x * blockDim.x + threadIdx.x;
    if (i >= (long)TOK * 16) return;
    int r = (int)(i & 15);
    long tok = i >> 4;
    int s = (int)(tok % S_);
    const float* x = ckv + tok * KVRP_PAD + KVRANK_;
    float x1 = x[r], x2 = x[16 + r];
    float c1 = load_in(cosb, (long)s * ROPE_ + r, bf);
    float s1 = load_in(sinb, (long)s * ROPE_ + r, bf);
    float c2 = load_in(cosb, (long)s * ROPE_ + 16 + r, bf);
    float s2 = load_in(sinb, (long)s * ROPE_ + 16 + r, bf);
    krot[tok * ROPE_ + r]      = f2bf(x1 * c1 - x2 * s1);
    krot[tok * ROPE_ + 16 + r] = f2bf(x2 * c2 + x1 * s2);
}

// ---- bf16 MFMA GEMM (m93 structure)
__global__ __launch_bounds__(256) void k_gemm(const unsigned short* A, const unsigned short* Bt,
                                              void* C, int M, int N, int K,
                                              int out_mode, const int* flag) {
    int obf = (out_mode == 2) ? flag[0] : out_mode;
    __shared__ __align__(16) unsigned short As[128][40];
    __shared__ __align__(16) unsigned short Bs[128][40];
    int tid = threadIdx.x;
    int gm = blockIdx.y * 128, gn = blockIdx.x * 128;
    int lane = tid & 63, w = tid >> 6, wm = w >> 1, wn = w & 1;
    int g = lane >> 4, qi = lane & 15;
    floatx4 acc[4][4];
#pragma unroll
    for (int mt = 0; mt < 4; mt++)
#pragma unroll
        for (int nt = 0; nt < 4; nt++) acc[mt][nt] = (floatx4){0.f, 0.f, 0.f, 0.f};

    for (int k0 = 0; k0 < K; k0 += 32) {
        __syncthreads();
#pragma unroll
        for (int i = 0; i < 2; i++) {
            int c = tid + i * 256;
            int row = c >> 2, kc = (c & 3) * 8;
            *(ushort8_t*)&As[row][kc] = *(const ushort8_t*)&A[(long)(gm + row) * K + k0 + kc];
            *(ushort8_t*)&Bs[row][kc] = *(const ushort8_t*)&Bt[(long)(gn + row) * K + k0 + kc];
        }
        __syncthreads();
        bf16x8 fa[4], fb[4];
#pragma unroll
        for (int mt = 0; mt < 4; mt++) fa[mt] = *(const bf16x8*)&As[wm * 64 + mt * 16 + qi][g * 8];
#pragma unroll
        for (int nt = 0; nt < 4; nt++) fb[nt] = *(const bf16x8*)&Bs[wn * 64 + nt * 16 + qi][g * 8];
#pragma unroll
        for (int mt = 0; mt < 4; mt++)
#pragma unroll
            for (int nt = 0; nt < 4; nt++)
                acc[mt][nt] = __builtin_amdgcn_mfma_f32_16x16x32_bf16(fa[mt], fb[nt], acc[mt][nt], 0, 0, 0);
    }
#pragma unroll
    for (int mt = 0; mt < 4; mt++)
#pragma unroll
        for (int nt = 0; nt < 4; nt++)
#pragma unroll
            for (int r = 0; r < 4; r++) {
                long row = gm + wm * 64 + mt * 16 + g * 4 + r;
                long col = gn + wn * 64 + nt * 16 + qi;
                float v = acc[mt][nt][r];
                if (obf) ((unsigned short*)C)[row * N + col] = f2bf(v);
                else     ((float*)C)[row * N + col] = v;
            }
}

// ---- flash attention v2: block = (b, h, 64 q rows), 4 waves x 16 rows.
// K-loop tiles 64 keys staged in LDS (K: pass+rot fused rows of 96; V: transposed).
// S^T = K*Q^T so P exits QK^T directly in PV A-operand layout.
__global__ __launch_bounds__(256) void k_attn(const unsigned short* q, const unsigned short* kv,
                                              const unsigned short* krot, const unsigned short* vt,
                                              unsigned short* out) {
    __shared__ __align__(16) unsigned short Ks[64][104];  // 64 keys x (64 pass + 32 rope), pad->104
    __shared__ __align__(16) unsigned short Vs[64][80];   // 64 vd x 64 keys, pad->80
    int tid = threadIdx.x;
    int lane = tid & 63, w = tid >> 6;
    int b = blockIdx.z, h = blockIdx.y;
    int qblk = gridDim.x - 1 - blockIdx.x;    // longest blocks first
    int g = lane >> 4, qi = lane & 15;
    long tok0 = (long)b * S_;
    int qrow = qblk * 64 + w * 16 + qi;

    const unsigned short* qp = q + (tok0 + qrow) * HQKD + h * QKD_;
    bf16x8 fq[3];
#pragma unroll
    for (int c = 0; c < 3; c++) fq[c] = *(const bf16x8*)&qp[c * 32 + g * 8];

    const unsigned short* kbase = kv + tok0 * HKV + h * 128;
    const unsigned short* vtb = vt + ((long)(b * H_ + h) * 64) * S_;

    floatx4 o[4];
#pragma unroll
    for (int vc = 0; vc < 4; vc++) o[vc] = (floatx4){0.f, 0.f, 0.f, 0.f};
    float m = -1e30f, lsum = 0.f;

    for (int kt = 0; kt <= qblk; kt++) {
        int k0 = kt * 64;
        __syncthreads();
        // stage K-pass: 64 rows x 64 shorts
#pragma unroll
        for (int i = 0; i < 2; i++) {
            int idx = tid + i * 256;
            int row = idx >> 3, part = idx & 7;
            *(ushort8_t*)&Ks[row][part * 8] =
                *(const ushort8_t*)&kbase[(long)(k0 + row) * HKV + part * 8];
        }
        // stage K-rope: 64 rows x 32 shorts
        {
            int row = tid >> 2, part = tid & 3;
            *(ushort8_t*)&Ks[row][64 + part * 8] =
                *(const ushort8_t*)&krot[(long)(tok0 + k0 + row) * ROPE_ + part * 8];
        }
        // stage V^T: 64 vd rows x 64 keys
#pragma unroll
        for (int i = 0; i < 2; i++) {
            int idx = tid + i * 256;
            int row = idx >> 3, part = idx & 7;
            *(ushort8_t*)&Vs[row][part * 8] =
                *(const ushort8_t*)&vtb[(long)row * S_ + k0 + part * 8];
        }
        __syncthreads();

        int kkmax = (kt == qblk) ? w : 3;
        for (int kk = 0; kk <= kkmax; kk++) {
            bf16x8 fk0 = *(const bf16x8*)&Ks[kk * 16 + qi][g * 8];
            bf16x8 fk1 = *(const bf16x8*)&Ks[kk * 16 + qi][32 + g * 8];
            bf16x8 fk2 = *(const bf16x8*)&Ks[kk * 16 + qi][64 + g * 8];
            floatx4 st = (floatx4){0.f, 0.f, 0.f, 0.f};
            st = __builtin_amdgcn_mfma_f32_16x16x32_bf16(fk0, fq[0], st, 0, 0, 0);
            st = __builtin_amdgcn_mfma_f32_16x16x32_bf16(fk1, fq[1], st, 0, 0, 0);
            st = __builtin_amdgcn_mfma_f32_16x16x32_bf16(fk2, fq[2], st, 0, 0, 0);
            // st[r] = S^T[key kk*16+g*4+r][q = qi]
            bool diag = (kt == qblk) && (kk == w);
            float sv[4], tmax = -3e30f;
#pragma unroll
            for (int r = 0; r < 4; r++) {
                float s = st[r] * SCALING_;
                if (diag && (g * 4 + r) > qi) s = -1e30f;
                sv[r] = s;
                tmax = fmaxf(tmax, s);
            }
            tmax = fmaxf(tmax, __shfl_xor(tmax, 16, 64));
            tmax = fmaxf(tmax, __shfl_xor(tmax, 32, 64));
            float mnew = fmaxf(m, tmax);
            float alpha = __expf(m - mnew);
            float ps = 0.f;
            shortx4 fp;
#pragma unroll
            for (int r = 0; r < 4; r++) {
                float p = __expf(sv[r] - mnew);
                ps += p;
                fp[r] = (short)f2bf(p);
            }
            ps += __shfl_xor(ps, 16, 64);
            ps += __shfl_xor(ps, 32, 64);
            lsum = lsum * alpha + ps;
            m = mnew;
            float ar[4];
#pragma unroll
            for (int r = 0; r < 4; r++) ar[r] = __shfl(alpha, (lane & 48) | (g * 4 + r), 64);
#pragma unroll
            for (int vc = 0; vc < 4; vc++) {
                o[vc][0] *= ar[0]; o[vc][1] *= ar[1]; o[vc][2] *= ar[2]; o[vc][3] *= ar[3];
            }
#pragma unroll
            for (int vc = 0; vc < 4; vc++) {
                shortx4 fv = *(const shortx4*)&Vs[vc * 16 + qi][kk * 16 + g * 4];
                o[vc] = __builtin_amdgcn_mfma_f32_16x16x16bf16_1k(fp, fv, o[vc], 0, 0, 0);
            }
        }
    }
    float lr[4];
#pragma unroll
    for (int r = 0; r < 4; r++) lr[r] = __shfl(lsum, (lane & 48) | (g * 4 + r), 64);
#pragma unroll
    for (int vc = 0; vc < 4; vc++)
#pragma unroll
        for (int r = 0; r < 4; r++)
            out[(tok0 + qblk * 64 + w * 16 + g * 4 + r) * HVD + h * VD_ + vc * 16 + qi] =
                f2bf(o[vc][r] / lr[r]);
}

extern "C" void kernel_launch(void* const* d_in, const int* in_sizes, int n_in,
                              void* d_out, int out_size, void* d_ws, size_t ws_size,
                              hipStream_t stream) {
    const void* hidden = d_in[0];
    const void* cosb   = d_in[1];
    const void* sinb   = d_in[2];
    const void* wq_a   = d_in[3];
    const void* q_ln   = d_in[4];
    const void* wq_b   = d_in[5];
    const void* wkv_a  = d_in[6];
    const void* kv_ln  = d_in[7];
    const void* wkv_b  = d_in[8];
    const void* wo     = d_in[9];

    char* ws = (char*)d_ws;
    size_t off = 0;
    auto alloc = [&](size_t bytes) -> void* {
        void* p = ws + off;
        off += (bytes + 255) & ~(size_t)255;
        return p;
    };
    int* flag                = (int*)alloc(256);
    unsigned short* hbf      = (unsigned short*)alloc((size_t)TOK * HID_ * 2);  // reused as vt later
    unsigned short* wqa_t    = (unsigned short*)alloc((size_t)QRANK_ * HID_ * 2);
    unsigned short* wqb_t    = (unsigned short*)alloc((size_t)HQKD * QRANK_ * 2);
    unsigned short* wkva_t   = (unsigned short*)alloc((size_t)KVRP_PAD * HID_ * 2);
    unsigned short* wkvb_t   = (unsigned short*)alloc((size_t)HKV * KVRANK_ * 2);
    unsigned short* wo_t     = (unsigned short*)alloc((size_t)HID_ * HVD * 2);
    float*          q_a      = (float*)alloc((size_t)TOK * QRANK_ * 4);
    unsigned short* q_a_n    = (unsigned short*)alloc((size_t)TOK * QRANK_ * 2);
    unsigned short* q_raw    = (unsigned short*)alloc((size_t)TOK * HQKD * 2);
    float*          ckv      = (float*)alloc((size_t)TOK * KVRP_PAD * 4);
    unsigned short* kc_n     = (unsigned short*)alloc((size_t)TOK * KVRANK_ * 2);
    unsigned short* kv_raw   = (unsigned short*)alloc((size_t)TOK * HKV * 2);
    unsigned short* krot     = (unsigned short*)alloc((size_t)TOK * ROPE_ * 2);
    unsigned short* attn_o   = (unsigned short*)alloc((size_t)TOK * HVD * 2);
    unsigned short* vt       = hbf;  // hbf dead after the two A-gemms; same elem count

    k_detect<<<1, 64, 0, stream>>>((const unsigned short*)cosb, flag);

    long nh = (long)TOK * HID_;
    k_tobf<<<(int)((nh + 255) / 256), 256, 0, stream>>>(hidden, hbf, nh, flag);

    k_transpose<<<dim3(HID_ / 32, QRANK_ / 32), 256, 0, stream>>>(wq_a, wqa_t, HID_, QRANK_, QRANK_, flag);
    k_transpose<<<dim3(QRANK_ / 32, HQKD / 32), 256, 0, stream>>>(wq_b, wqb_t, QRANK_, HQKD, HQKD, flag);
    k_transpose<<<dim3(HID_ / 32, KVRP_PAD / 32), 256, 0, stream>>>(wkv_a, wkva_t, HID_, KVRP_, KVRP_PAD, flag);
    k_transpose<<<dim3(KVRANK_ / 32, HKV / 32), 256, 0, stream>>>(wkv_b, wkvb_t, KVRANK_, HKV, HKV, flag);
    k_transpose<<<dim3(HVD / 32, HID_ / 32), 256, 0, stream>>>(wo, wo_t, HVD, HID_, HID_, flag);

    // q chain
    k_gemm<<<dim3(QRANK_ / 128, TOK / 128), 256, 0, stream>>>(hbf, wqa_t, q_a, TOK, QRANK_, HID_, 0, flag);
    k_rmsnorm<<<TOK, 256, 0, stream>>>(q_a, QRANK_, QRANK_, q_ln, q_a_n, QRANK_, flag);
    k_gemm<<<dim3(HQKD / 128, TOK / 128), 256, 0, stream>>>(q_a_n, wqb_t, q_raw, TOK, HQKD, QRANK_, 1, flag);

    // kv chain
    k_gemm<<<dim3(KVRP_PAD / 128, TOK / 128), 256, 0, stream>>>(hbf, wkva_t, ckv, TOK, KVRP_PAD, HID_, 0, flag);
    k_rmsnorm<<<TOK, 256, 0, stream>>>(ckv, KVRP_PAD, KVRANK_, kv_ln, kc_n, KVRANK_, flag);
    k_gemm<<<dim3(HKV / 128, TOK / 128), 256, 0, stream>>>(kc_n, wkvb_t, kv_raw, TOK, HKV, KVRANK_, 1, flag);

    // rope
    long nrq = (long)TOK * H_ * 16;
    k_rope_q<<<(int)((nrq + 255) / 256), 256, 0, stream>>>(q_raw, cosb, sinb, flag);
    long nrk = (long)TOK * 16;
    k_rope_k<<<(int)((nrk + 255) / 256), 256, 0, stream>>>(ckv, krot, cosb, sinb, flag);

    // V transpose (into dead hbf buffer), then attention
    k_vtrans<<<dim3(S_ / 32, VD_ / 32, B_ * H_), 256, 0, stream>>>(kv_raw, vt);
    k_attn<<<dim3(S_ / 64, H_, B_), 256, 0, stream>>>(q_raw, kv_raw, krot, vt, attn_o);

    // output projection (dtype per detected mode)
    k_gemm<<<dim3(HID_ / 128, TOK / 128), 256, 0, stream>>>(attn_o, wo_t, d_out, TOK, HID_, HVD, 2, flag);
}

// Round 4
// 812.007 us; speedup vs baseline: 1.2722x; 1.0756x over previous
//
#include <hip/hip_runtime.h>
#include <hip/hip_bf16.h>
#include <cstdint>

#define B_ 2
#define S_ 2048
#define HID_ 2560
#define H_ 40
#define NOPE_ 64
#define ROPE_ 32
#define VD_ 64
#define QKD_ 96
#define QRANK_ 768
#define KVRANK_ 256
#define KVRP_ 288
#define KVRP_PAD 384
#define HQKD (H_*QKD_)          // 3840
#define HKV  (H_*(NOPE_+VD_))   // 5120
#define HVD  (H_*VD_)           // 2560
#define TOK  (B_*S_)            // 4096
#define EPS_ 1e-5f
#define SCALING_ 0.10206207261596575f

typedef __bf16  bf16x8  __attribute__((ext_vector_type(8)));
typedef float   floatx4 __attribute__((ext_vector_type(4)));
typedef short   shortx4 __attribute__((ext_vector_type(4)));
typedef unsigned short ushort8_t __attribute__((ext_vector_type(8)));

__device__ __forceinline__ unsigned short f2bf(float f) {
    unsigned int u = __builtin_bit_cast(unsigned int, f);
    unsigned int r = (u + 0x7FFFu + ((u >> 16) & 1u)) >> 16;  // RNE
    return (unsigned short)r;
}
__device__ __forceinline__ float bf2f(unsigned short h) {
    return __builtin_bit_cast(float, ((unsigned int)h) << 16);
}
__device__ __forceinline__ float load_in(const void* p, long i, int bf) {
    if (bf) return bf2f(((const unsigned short*)p)[i]);
    return ((const float*)p)[i];
}

// async global->LDS, 16B per lane. LDS dest = wave-uniform base + lane*16.
__device__ __forceinline__ void gl_lds16(const unsigned short* g, unsigned short* l) {
    __builtin_amdgcn_global_load_lds(
        (const __attribute__((address_space(1))) unsigned int*)g,
        (__attribute__((address_space(3))) unsigned int*)l, 16, 0, 0);
}

// ---- dtype detector: cos[0]==1.0 -> f32 stores 0x0000 in first half-word,
// bf16 stores 0x3F80.
__global__ void k_detect(const unsigned short* cosb, int* flag) {
    if (threadIdx.x == 0) flag[0] = (cosb[0] != 0) ? 1 : 0;
}

__global__ void k_tobf(const void* in, unsigned short* out, long n, const int* flag) {
    int bf = flag[0];
    long i = (long)blockIdx.x * blockDim.x + threadIdx.x;
    if (i >= n) return;
    out[i] = bf ? ((const unsigned short*)in)[i] : f2bf(((const float*)in)[i]);
}

// ---- LDS-tiled transpose+cast: in [K][N] -> out bf16 [Npad][K], zero-fill n>=N
__global__ __launch_bounds__(256) void k_transpose(const void* in, unsigned short* out,
                                                   int K, int N, int Npad, const int* flag) {
    __shared__ float tile[32][33];
    int bf = flag[0];
    int k0 = blockIdx.x * 32;
    int n0 = blockIdx.y * 32;
    int tx = threadIdx.x & 31, ty = threadIdx.x >> 5;
#pragma unroll
    for (int i = 0; i < 4; i++) {
        int k = k0 + ty + 8 * i, n = n0 + tx;
        float v = 0.f;
        if (n < N && k < K) v = load_in(in, (long)k * N + n, bf);
        tile[ty + 8 * i][tx] = v;
    }
    __syncthreads();
#pragma unroll
    for (int i = 0; i < 4; i++) {
        int n = n0 + ty + 8 * i, k = k0 + tx;
        if (n < Npad && k < K) out[(long)n * K + k] = f2bf(tile[tx][ty + 8 * i]);
    }
}

// ---- transpose V out of kv_raw: [tok][h*128+64+vd] -> vt[(b*H+h)*64+vd][S]
__global__ __launch_bounds__(256) void k_vtrans(const unsigned short* kv, unsigned short* vt) {
    __shared__ unsigned short t[32][33];
    int bh = blockIdx.z;
    int s0 = blockIdx.x * 32, v0 = blockIdx.y * 32;
    int b = bh / H_, h = bh % H_;
    int tx = threadIdx.x & 31, ty = threadIdx.x >> 5;
#pragma unroll
    for (int i = 0; i < 4; i++) {
        int s = s0 + ty + 8 * i, vd = v0 + tx;
        t[ty + 8 * i][tx] = kv[((long)b * S_ + s) * HKV + h * 128 + 64 + vd];
    }
    __syncthreads();
#pragma unroll
    for (int i = 0; i < 4; i++) {
        int vd = v0 + ty + 8 * i, s = s0 + tx;
        vt[((long)bh * 64 + vd) * S_ + s] = t[tx][ty + 8 * i];
    }
}

// ---- RMSNorm
__global__ __launch_bounds__(256) void k_rmsnorm(const float* in, int ldin, int L,
                                                 const void* w, unsigned short* out,
                                                 int ldout, const int* flag) {
    int bf = flag[0];
    long row = blockIdx.x;
    const float* x = in + row * ldin;
    float ss = 0.f;
    for (int i = threadIdx.x; i < L; i += 256) { float v = x[i]; ss += v * v; }
    __shared__ float red[256];
    red[threadIdx.x] = ss;
    __syncthreads();
    for (int s = 128; s > 0; s >>= 1) {
        if (threadIdx.x < s) red[threadIdx.x] += red[threadIdx.x + s];
        __syncthreads();
    }
    float scale = rsqrtf(red[0] / (float)L + EPS_);
    for (int i = threadIdx.x; i < L; i += 256)
        out[row * ldout + i] = f2bf(x[i] * scale * load_in(w, i, bf));
}

// ---- RoPE on q (in-place, bf16)
__global__ void k_rope_q(unsigned short* q, const void* cosb, const void* sinb, const int* flag) {
    int bf = flag[0];
    long i = (long)blockIdx.x * blockDim.x + threadIdx.x;
    if (i >= (long)TOK * H_ * 16) return;
    int r = (int)(i & 15);
    long t = i >> 4;
    int h = (int)(t % H_);
    long tok = t / H_;
    int s = (int)(tok % S_);
    long base = tok * HQKD + h * QKD_ + NOPE_;
    float x1 = bf2f(q[base + r]), x2 = bf2f(q[base + 16 + r]);
    float c1 = load_in(cosb, (long)s * ROPE_ + r, bf);
    float s1 = load_in(sinb, (long)s * ROPE_ + r, bf);
    float c2 = load_in(cosb, (long)s * ROPE_ + 16 + r, bf);
    float s2 = load_in(sinb, (long)s * ROPE_ + 16 + r, bf);
    q[base + r]      = f2bf(x1 * c1 - x2 * s1);
    q[base + 16 + r] = f2bf(x2 * c2 + x1 * s2);
}

// ---- RoPE on shared k_rot
__global__ void k_rope_k(const float* ckv, unsigned short* krot,
                         const void* cosb, const void* sinb, const int* flag) {
    int bf = flag[0];
    long i = (long)blockIdx.x * blockDim.x + threadIdx.x;
    if (i >= (long)TOK * 16) return;
    int r = (int)(i & 15);
    long tok = i >> 4;
    int s = (int)(tok % S_);
    const float* x = ckv + tok * KVRP_PAD + KVRANK_;
    float x1 = x[r], x2 = x[16 + r];
    float c1 = load_in(cosb, (long)s * ROPE_ + r, bf);
    float s1 = load_in(sinb, (long)s * ROPE_ + r, bf);
    float c2 = load_in(cosb, (long)s * ROPE_ + 16 + r, bf);
    float s2 = load_in(sinb, (long)s * ROPE_ + 16 + r, bf);
    krot[tok * ROPE_ + r]      = f2bf(x1 * c1 - x2 * s1);
    krot[tok * ROPE_ + 16 + r] = f2bf(x2 * c2 + x1 * s2);
}

// ---- bf16 MFMA GEMM, m97 structure: unpadded LDS + global_load_lds width-16
__global__ __launch_bounds__(256) void k_gemm(const unsigned short* A, const unsigned short* Bt,
                                              void* C, int M, int N, int K,
                                              int out_mode, const int* flag) {
    int obf = (out_mode == 2) ? flag[0] : out_mode;
    __shared__ __align__(16) unsigned short As[128 * 32];
    __shared__ __align__(16) unsigned short Bs[128 * 32];
    int tid = threadIdx.x;
    int gm = blockIdx.y * 128, gn = blockIdx.x * 128;
    int lane = tid & 63, w = tid >> 6, wm = w >> 1, wn = w & 1;
    int g = lane >> 4, qi = lane & 15;
    // staging: chunk c (16 rows x 32 shorts = 1KB); wave w does chunks {w, w+4}
    int srow = lane >> 2;          // 0..15
    int scol = (lane & 3) * 8;     // 0,8,16,24
    const unsigned short* Ag0 = A  + (long)(gm + w * 16 + srow) * K + scol;
    const unsigned short* Ag1 = A  + (long)(gm + (w + 4) * 16 + srow) * K + scol;
    const unsigned short* Bg0 = Bt + (long)(gn + w * 16 + srow) * K + scol;
    const unsigned short* Bg1 = Bt + (long)(gn + (w + 4) * 16 + srow) * K + scol;
    unsigned short* Al0 = &As[w * 512];
    unsigned short* Al1 = &As[(w + 4) * 512];
    unsigned short* Bl0 = &Bs[w * 512];
    unsigned short* Bl1 = &Bs[(w + 4) * 512];

    floatx4 acc[4][4];
#pragma unroll
    for (int mt = 0; mt < 4; mt++)
#pragma unroll
        for (int nt = 0; nt < 4; nt++) acc[mt][nt] = (floatx4){0.f, 0.f, 0.f, 0.f};

    for (int k0 = 0; k0 < K; k0 += 32) {
        __syncthreads();
        gl_lds16(Ag0 + k0, Al0);
        gl_lds16(Ag1 + k0, Al1);
        gl_lds16(Bg0 + k0, Bl0);
        gl_lds16(Bg1 + k0, Bl1);
        __syncthreads();
        bf16x8 fa[4], fb[4];
#pragma unroll
        for (int mt = 0; mt < 4; mt++) fa[mt] = *(const bf16x8*)&As[(wm * 64 + mt * 16 + qi) * 32 + g * 8];
#pragma unroll
        for (int nt = 0; nt < 4; nt++) fb[nt] = *(const bf16x8*)&Bs[(wn * 64 + nt * 16 + qi) * 32 + g * 8];
#pragma unroll
        for (int mt = 0; mt < 4; mt++)
#pragma unroll
            for (int nt = 0; nt < 4; nt++)
                acc[mt][nt] = __builtin_amdgcn_mfma_f32_16x16x32_bf16(fa[mt], fb[nt], acc[mt][nt], 0, 0, 0);
    }
#pragma unroll
    for (int mt = 0; mt < 4; mt++)
#pragma unroll
        for (int nt = 0; nt < 4; nt++)
#pragma unroll
            for (int r = 0; r < 4; r++) {
                long row = gm + wm * 64 + mt * 16 + g * 4 + r;
                long col = gn + wn * 64 + nt * 16 + qi;
                float v = acc[mt][nt][r];
                if (obf) ((unsigned short*)C)[row * N + col] = f2bf(v);
                else     ((float*)C)[row * N + col] = v;
            }
}

// ---- flash attention v3: block = (b, h, 128 q rows), 4 waves x 32 q rows (2 tiles).
// Per 64-key LDS tile: kk-outer QK (K frags loaded once), ONE batched online-softmax
// round per q-tile, fv hoisted across q-tiles in PV. Per-wave ktmax skips masked tiles.
__global__ __launch_bounds__(256) void k_attn(const unsigned short* q, const unsigned short* kv,
                                              const unsigned short* krot, const unsigned short* vt,
                                              unsigned short* out) {
    __shared__ __align__(16) unsigned short Ks[64 * 96];  // key-major, 64+32 fused, stride 96
    __shared__ __align__(16) unsigned short Vs[64 * 80];  // vd-major V^T, stride 80
    int tid = threadIdx.x;
    int lane = tid & 63, w = tid >> 6;
    int b = blockIdx.z, h = blockIdx.y;
    int qblk = gridDim.x - 1 - blockIdx.x;   // longest first
    int qbase = qblk * 128;
    int g = lane >> 4, qi = lane & 15;
    long tok0 = (long)b * S_;

    bf16x8 fq[2][3];
#pragma unroll
    for (int qt = 0; qt < 2; qt++) {
        const unsigned short* qp = q + (tok0 + qbase + w * 32 + qt * 16 + qi) * HQKD + h * QKD_;
#pragma unroll
        for (int c = 0; c < 3; c++) fq[qt][c] = *(const bf16x8*)&qp[c * 32 + g * 8];
    }

    const unsigned short* kbase = kv + tok0 * HKV + h * 128;
    const unsigned short* krb   = krot + tok0 * ROPE_;
    const unsigned short* vtb   = vt + ((long)(b * H_ + h) * 64) * S_;

    floatx4 o[2][4];
#pragma unroll
    for (int qt = 0; qt < 2; qt++)
#pragma unroll
        for (int vc = 0; vc < 4; vc++) o[qt][vc] = (floatx4){0.f, 0.f, 0.f, 0.f};
    float m[2] = {-1e30f, -1e30f}, l[2] = {0.f, 0.f};

    int ktb = 2 * qblk + 2;
    int ktmax_w = (qbase + w * 32 + 31) >> 6;

    for (int kt = 0; kt < ktb; kt++) {
        int k0 = kt * 64;
        __syncthreads();
        // stage K (pass cols 0..63 from kv, rope cols 64..95 from krot): 768 8-short chunks
#pragma unroll
        for (int i = 0; i < 3; i++) {
            int idx = tid + i * 256;
            int row = idx / 12, c = (idx % 12) * 8;
            const unsigned short* src = (c < 64)
                ? kbase + (long)(k0 + row) * HKV + c
                : krb + (long)(k0 + row) * ROPE_ + (c - 64);
            *(ushort8_t*)&Ks[row * 96 + c] = *(const ushort8_t*)src;
        }
        // stage V^T: 512 chunks
#pragma unroll
        for (int i = 0; i < 2; i++) {
            int idx = tid + i * 256;
            int row = idx >> 3, c = (idx & 7) * 8;
            *(ushort8_t*)&Vs[row * 80 + c] = *(const ushort8_t*)&vtb[(long)row * S_ + k0 + c];
        }
        __syncthreads();
        if (kt > ktmax_w) continue;   // stage-only for waves already past their causal limit

        // ---- QK^T: kk-outer so each K fragment is read once
        floatx4 st[2][4];
#pragma unroll
        for (int kk = 0; kk < 4; kk++) {
            const unsigned short* kr = &Ks[(kk * 16 + qi) * 96];
            bf16x8 fk0 = *(const bf16x8*)&kr[g * 8];
            bf16x8 fk1 = *(const bf16x8*)&kr[32 + g * 8];
            bf16x8 fk2 = *(const bf16x8*)&kr[64 + g * 8];
#pragma unroll
            for (int qt = 0; qt < 2; qt++) {
                floatx4 s = (floatx4){0.f, 0.f, 0.f, 0.f};
                s = __builtin_amdgcn_mfma_f32_16x16x32_bf16(fk0, fq[qt][0], s, 0, 0, 0);
                s = __builtin_amdgcn_mfma_f32_16x16x32_bf16(fk1, fq[qt][1], s, 0, 0, 0);
                s = __builtin_amdgcn_mfma_f32_16x16x32_bf16(fk2, fq[qt][2], s, 0, 0, 0);
                st[qt][kk] = s;
            }
        }

        // ---- batched online softmax: one reduction round per q-tile per 64 keys
        shortx4 fp[2][4];
#pragma unroll
        for (int qt = 0; qt < 2; qt++) {
            int qrow = qbase + w * 32 + qt * 16 + qi;
            // mask needed iff max_key (k0+63) can exceed the SMALLEST q-row of
            // this 16-row tile (qbase + w*32 + qt*16). (R3 bug: compared vs +15.)
            bool need_mask = (k0 + 63) > (qbase + w * 32 + qt * 16);  // wave-uniform
            float sv[4][4];
            float tmax = -3e30f;
#pragma unroll
            for (int kk = 0; kk < 4; kk++)
#pragma unroll
                for (int r = 0; r < 4; r++) {
                    float s = st[qt][kk][r] * SCALING_;
                    if (need_mask && (k0 + kk * 16 + g * 4 + r) > qrow) s = -1e30f;
                    sv[kk][r] = s;
                    tmax = fmaxf(tmax, s);
                }
            tmax = fmaxf(tmax, __shfl_xor(tmax, 16, 64));
            tmax = fmaxf(tmax, __shfl_xor(tmax, 32, 64));
            float mnew = fmaxf(m[qt], tmax);
            float alpha = __expf(m[qt] - mnew);
            float ps = 0.f;
#pragma unroll
            for (int kk = 0; kk < 4; kk++)
#pragma unroll
                for (int r = 0; r < 4; r++) {
                    float p = __expf(sv[kk][r] - mnew);
                    ps += p;
                    fp[qt][kk][r] = (short)f2bf(p);
                }
            ps += __shfl_xor(ps, 16, 64);
            ps += __shfl_xor(ps, 32, 64);
            l[qt] = l[qt] * alpha + ps;
            m[qt] = mnew;
            float ar[4];
#pragma unroll
            for (int r = 0; r < 4; r++) ar[r] = __shfl(alpha, (lane & 48) | (g * 4 + r), 64);
#pragma unroll
            for (int vc = 0; vc < 4; vc++) {
                o[qt][vc][0] *= ar[0]; o[qt][vc][1] *= ar[1];
                o[qt][vc][2] *= ar[2]; o[qt][vc][3] *= ar[3];
            }
        }

        // ---- PV: fv loaded once per kk, shared by both q-tiles
#pragma unroll
        for (int kk = 0; kk < 4; kk++) {
            shortx4 fv[4];
#pragma unroll
            for (int vc = 0; vc < 4; vc++)
                fv[vc] = *(const shortx4*)&Vs[(vc * 16 + qi) * 80 + kk * 16 + g * 4];
#pragma unroll
            for (int qt = 0; qt < 2; qt++)
#pragma unroll
                for (int vc = 0; vc < 4; vc++)
                    o[qt][vc] = __builtin_amdgcn_mfma_f32_16x16x16bf16_1k(fp[qt][kk], fv[vc], o[qt][vc], 0, 0, 0);
        }
    }

#pragma unroll
    for (int qt = 0; qt < 2; qt++) {
        float lr[4];
#pragma unroll
        for (int r = 0; r < 4; r++) lr[r] = __shfl(l[qt], (lane & 48) | (g * 4 + r), 64);
#pragma unroll
        for (int vc = 0; vc < 4; vc++)
#pragma unroll
            for (int r = 0; r < 4; r++)
                out[(tok0 + qbase + w * 32 + qt * 16 + g * 4 + r) * HVD + h * VD_ + vc * 16 + qi] =
                    f2bf(o[qt][vc][r] / lr[r]);
    }
}

extern "C" void kernel_launch(void* const* d_in, const int* in_sizes, int n_in,
                              void* d_out, int out_size, void* d_ws, size_t ws_size,
                              hipStream_t stream) {
    const void* hidden = d_in[0];
    const void* cosb   = d_in[1];
    const void* sinb   = d_in[2];
    const void* wq_a   = d_in[3];
    const void* q_ln   = d_in[4];
    const void* wq_b   = d_in[5];
    const void* wkv_a  = d_in[6];
    const void* kv_ln  = d_in[7];
    const void* wkv_b  = d_in[8];
    const void* wo     = d_in[9];

    char* ws = (char*)d_ws;
    size_t off = 0;
    auto alloc = [&](size_t bytes) -> void* {
        void* p = ws + off;
        off += (bytes + 255) & ~(size_t)255;
        return p;
    };
    int* flag                = (int*)alloc(256);
    unsigned short* hbf      = (unsigned short*)alloc((size_t)TOK * HID_ * 2);  // reused as vt later
    unsigned short* wqa_t    = (unsigned short*)alloc((size_t)QRANK_ * HID_ * 2);
    unsigned short* wqb_t    = (unsigned short*)alloc((size_t)HQKD * QRANK_ * 2);
    unsigned short* wkva_t   = (unsigned short*)alloc((size_t)KVRP_PAD * HID_ * 2);
    unsigned short* wkvb_t   = (unsigned short*)alloc((size_t)HKV * KVRANK_ * 2);
    unsigned short* wo_t     = (unsigned short*)alloc((size_t)HID_ * HVD * 2);
    float*          q_a      = (float*)alloc((size_t)TOK * QRANK_ * 4);
    unsigned short* q_a_n    = (unsigned short*)alloc((size_t)TOK * QRANK_ * 2);
    unsigned short* q_raw    = (unsigned short*)alloc((size_t)TOK * HQKD * 2);
    float*          ckv      = (float*)alloc((size_t)TOK * KVRP_PAD * 4);
    unsigned short* kc_n     = (unsigned short*)alloc((size_t)TOK * KVRANK_ * 2);
    unsigned short* kv_raw   = (unsigned short*)alloc((size_t)TOK * HKV * 2);
    unsigned short* krot     = (unsigned short*)alloc((size_t)TOK * ROPE_ * 2);
    unsigned short* attn_o   = (unsigned short*)alloc((size_t)TOK * HVD * 2);
    unsigned short* vt       = hbf;  // hbf dead after the two A-gemms; same elem count

    k_detect<<<1, 64, 0, stream>>>((const unsigned short*)cosb, flag);

    long nh = (long)TOK * HID_;
    k_tobf<<<(int)((nh + 255) / 256), 256, 0, stream>>>(hidden, hbf, nh, flag);

    k_transpose<<<dim3(HID_ / 32, QRANK_ / 32), 256, 0, stream>>>(wq_a, wqa_t, HID_, QRANK_, QRANK_, flag);
    k_transpose<<<dim3(QRANK_ / 32, HQKD / 32), 256, 0, stream>>>(wq_b, wqb_t, QRANK_, HQKD, HQKD, flag);
    k_transpose<<<dim3(HID_ / 32, KVRP_PAD / 32), 256, 0, stream>>>(wkv_a, wkva_t, HID_, KVRP_, KVRP_PAD, flag);
    k_transpose<<<dim3(KVRANK_ / 32, HKV / 32), 256, 0, stream>>>(wkv_b, wkvb_t, KVRANK_, HKV, HKV, flag);
    k_transpose<<<dim3(HVD / 32, HID_ / 32), 256, 0, stream>>>(wo, wo_t, HVD, HID_, HID_, flag);

    // q chain
    k_gemm<<<dim3(QRANK_ / 128, TOK / 128), 256, 0, stream>>>(hbf, wqa_t, q_a, TOK, QRANK_, HID_, 0, flag);
    k_rmsnorm<<<TOK, 256, 0, stream>>>(q_a, QRANK_, QRANK_, q_ln, q_a_n, QRANK_, flag);
    k_gemm<<<dim3(HQKD / 128, TOK / 128), 256, 0, stream>>>(q_a_n, wqb_t, q_raw, TOK, HQKD, QRANK_, 1, flag);

    // kv chain
    k_gemm<<<dim3(KVRP_PAD / 128, TOK / 128), 256, 0, stream>>>(hbf, wkva_t, ckv, TOK, KVRP_PAD, HID_, 0, flag);
    k_rmsnorm<<<TOK, 256, 0, stream>>>(ckv, KVRP_PAD, KVRANK_, kv_ln, kc_n, KVRANK_, flag);
    k_gemm<<<dim3(HKV / 128, TOK / 128), 256, 0, stream>>>(kc_n, wkvb_t, kv_raw, TOK, HKV, KVRANK_, 1, flag);

    // rope
    long nrq = (long)TOK * H_ * 16;
    k_rope_q<<<(int)((nrq + 255) / 256), 256, 0, stream>>>(q_raw, cosb, sinb, flag);
    long nrk = (long)TOK * 16;
    k_rope_k<<<(int)((nrk + 255) / 256), 256, 0, stream>>>(ckv, krot, cosb, sinb, flag);

    // V transpose (into dead hbf buffer), then attention
    k_vtrans<<<dim3(S_ / 32, VD_ / 32, B_ * H_), 256, 0, stream>>>(kv_raw, vt);
    k_attn<<<dim3(S_ / 128, H_, B_), 256, 0, stream>>>(q_raw, kv_raw, krot, vt, attn_o);

    // output projection (dtype per detected mode)
    k_gemm<<<dim3(HID_ / 128, TOK / 128), 256, 0, stream>>>(attn_o, wo_t, d_out, TOK, HID_, HVD, 2, flag);
}

// Round 5
// 723.310 us; speedup vs baseline: 1.4282x; 1.1226x over previous
//
#include <hip/hip_runtime.h>
#include <hip/hip_bf16.h>
#include <cstdint>

#define B_ 2
#define S_ 2048
#define HID_ 2560
#define H_ 40
#define NOPE_ 64
#define ROPE_ 32
#define VD_ 64
#define QKD_ 96
#define QRANK_ 768
#define KVRANK_ 256
#define KVRP_ 288
#define KVRP_PAD 384
#define HQKD (H_*QKD_)          // 3840
#define HKV  (H_*(NOPE_+VD_))   // 5120
#define HVD  (H_*VD_)           // 2560
#define TOK  (B_*S_)            // 4096
#define EPS_ 1e-5f
#define SCALING_ 0.10206207261596575f

typedef __bf16  bf16x8  __attribute__((ext_vector_type(8)));
typedef float   floatx4 __attribute__((ext_vector_type(4)));
typedef short   shortx4 __attribute__((ext_vector_type(4)));
typedef unsigned short ushort8_t __attribute__((ext_vector_type(8)));

__device__ __forceinline__ unsigned short f2bf(float f) {
    unsigned int u = __builtin_bit_cast(unsigned int, f);
    unsigned int r = (u + 0x7FFFu + ((u >> 16) & 1u)) >> 16;  // RNE
    return (unsigned short)r;
}
__device__ __forceinline__ float bf2f(unsigned short h) {
    return __builtin_bit_cast(float, ((unsigned int)h) << 16);
}
__device__ __forceinline__ float load_in(const void* p, long i, int bf) {
    if (bf) return bf2f(((const unsigned short*)p)[i]);
    return ((const float*)p)[i];
}

// async global->LDS, 16B per lane. LDS dest = wave-uniform base + lane*16.
__device__ __forceinline__ void gl_lds16(const unsigned short* g, unsigned short* l) {
    __builtin_amdgcn_global_load_lds(
        (const __attribute__((address_space(1))) unsigned int*)g,
        (__attribute__((address_space(3))) unsigned int*)l, 16, 0, 0);
}

// ---- dtype detector: cos[0]==1.0 -> f32 stores 0x0000 in first half-word,
// bf16 stores 0x3F80.
__global__ void k_detect(const unsigned short* cosb, int* flag) {
    if (threadIdx.x == 0) flag[0] = (cosb[0] != 0) ? 1 : 0;
}

__global__ void k_tobf(const void* in, unsigned short* out, long n, const int* flag) {
    int bf = flag[0];
    long i = (long)blockIdx.x * blockDim.x + threadIdx.x;
    if (i >= n) return;
    out[i] = bf ? ((const unsigned short*)in)[i] : f2bf(((const float*)in)[i]);
}

// ---- LDS-tiled transpose+cast: in [K][N] -> out bf16 [Npad][K], zero-fill n>=N
__global__ __launch_bounds__(256) void k_transpose(const void* in, unsigned short* out,
                                                   int K, int N, int Npad, const int* flag) {
    __shared__ float tile[32][33];
    int bf = flag[0];
    int k0 = blockIdx.x * 32;
    int n0 = blockIdx.y * 32;
    int tx = threadIdx.x & 31, ty = threadIdx.x >> 5;
#pragma unroll
    for (int i = 0; i < 4; i++) {
        int k = k0 + ty + 8 * i, n = n0 + tx;
        float v = 0.f;
        if (n < N && k < K) v = load_in(in, (long)k * N + n, bf);
        tile[ty + 8 * i][tx] = v;
    }
    __syncthreads();
#pragma unroll
    for (int i = 0; i < 4; i++) {
        int n = n0 + ty + 8 * i, k = k0 + tx;
        if (n < Npad && k < K) out[(long)n * K + k] = f2bf(tile[tx][ty + 8 * i]);
    }
}

// ---- transpose V out of kv_raw: [tok][h*128+64+vd] -> vt[(b*H+h)*64+vd][S]
__global__ __launch_bounds__(256) void k_vtrans(const unsigned short* kv, unsigned short* vt) {
    __shared__ unsigned short t[32][33];
    int bh = blockIdx.z;
    int s0 = blockIdx.x * 32, v0 = blockIdx.y * 32;
    int b = bh / H_, h = bh % H_;
    int tx = threadIdx.x & 31, ty = threadIdx.x >> 5;
#pragma unroll
    for (int i = 0; i < 4; i++) {
        int s = s0 + ty + 8 * i, vd = v0 + tx;
        t[ty + 8 * i][tx] = kv[((long)b * S_ + s) * HKV + h * 128 + 64 + vd];
    }
    __syncthreads();
#pragma unroll
    for (int i = 0; i < 4; i++) {
        int vd = v0 + ty + 8 * i, s = s0 + tx;
        vt[((long)bh * 64 + vd) * S_ + s] = t[tx][ty + 8 * i];
    }
}

// ---- RMSNorm
__global__ __launch_bounds__(256) void k_rmsnorm(const float* in, int ldin, int L,
                                                 const void* w, unsigned short* out,
                                                 int ldout, const int* flag) {
    int bf = flag[0];
    long row = blockIdx.x;
    const float* x = in + row * ldin;
    float ss = 0.f;
    for (int i = threadIdx.x; i < L; i += 256) { float v = x[i]; ss += v * v; }
    __shared__ float red[256];
    red[threadIdx.x] = ss;
    __syncthreads();
    for (int s = 128; s > 0; s >>= 1) {
        if (threadIdx.x < s) red[threadIdx.x] += red[threadIdx.x + s];
        __syncthreads();
    }
    float scale = rsqrtf(red[0] / (float)L + EPS_);
    for (int i = threadIdx.x; i < L; i += 256)
        out[row * ldout + i] = f2bf(x[i] * scale * load_in(w, i, bf));
}

// ---- RoPE on q (in-place, bf16)
__global__ void k_rope_q(unsigned short* q, const void* cosb, const void* sinb, const int* flag) {
    int bf = flag[0];
    long i = (long)blockIdx.x * blockDim.x + threadIdx.x;
    if (i >= (long)TOK * H_ * 16) return;
    int r = (int)(i & 15);
    long t = i >> 4;
    int h = (int)(t % H_);
    long tok = t / H_;
    int s = (int)(tok % S_);
    long base = tok * HQKD + h * QKD_ + NOPE_;
    float x1 = bf2f(q[base + r]), x2 = bf2f(q[base + 16 + r]);
    float c1 = load_in(cosb, (long)s * ROPE_ + r, bf);
    float s1 = load_in(sinb, (long)s * ROPE_ + r, bf);
    float c2 = load_in(cosb, (long)s * ROPE_ + 16 + r, bf);
    float s2 = load_in(sinb, (long)s * ROPE_ + 16 + r, bf);
    q[base + r]      = f2bf(x1 * c1 - x2 * s1);
    q[base + 16 + r] = f2bf(x2 * c2 + x1 * s2);
}

// ---- RoPE on shared k_rot
__global__ void k_rope_k(const float* ckv, unsigned short* krot,
                         const void* cosb, const void* sinb, const int* flag) {
    int bf = flag[0];
    long i = (long)blockIdx.x * blockDim.x + threadIdx.x;
    if (i >= (long)TOK * 16) return;
    int r = (int)(i & 15);
    long tok = i >> 4;
    int s = (int)(tok % S_);
    const float* x = ckv + tok * KVRP_PAD + KVRANK_;
    float x1 = x[r], x2 = x[16 + r];
    float c1 = load_in(cosb, (long)s * ROPE_ + r, bf);
    float s1 = load_in(sinb, (long)s * ROPE_ + r, bf);
    float c2 = load_in(cosb, (long)s * ROPE_ + 16 + r, bf);
    float s2 = load_in(sinb, (long)s * ROPE_ + 16 + r, bf);
    krot[tok * ROPE_ + r]      = f2bf(x1 * c1 - x2 * s1);
    krot[tok * ROPE_ + 16 + r] = f2bf(x2 * c2 + x1 * s2);
}

// ---- bf16 MFMA GEMM, m97 structure: unpadded LDS + global_load_lds width-16
__global__ __launch_bounds__(256) void k_gemm(const unsigned short* A, const unsigned short* Bt,
                                              void* C, int M, int N, int K,
                                              int out_mode, const int* flag) {
    int obf = (out_mode == 2) ? flag[0] : out_mode;
    __shared__ __align__(16) unsigned short As[128 * 32];
    __shared__ __align__(16) unsigned short Bs[128 * 32];
    int tid = threadIdx.x;
    int gm = blockIdx.y * 128, gn = blockIdx.x * 128;
    int lane = tid & 63, w = tid >> 6, wm = w >> 1, wn = w & 1;
    int g = lane >> 4, qi = lane & 15;
    // staging: chunk c (16 rows x 32 shorts = 1KB); wave w does chunks {w, w+4}
    int srow = lane >> 2;          // 0..15
    int scol = (lane & 3) * 8;     // 0,8,16,24
    const unsigned short* Ag0 = A  + (long)(gm + w * 16 + srow) * K + scol;
    const unsigned short* Ag1 = A  + (long)(gm + (w + 4) * 16 + srow) * K + scol;
    const unsigned short* Bg0 = Bt + (long)(gn + w * 16 + srow) * K + scol;
    const unsigned short* Bg1 = Bt + (long)(gn + (w + 4) * 16 + srow) * K + scol;
    unsigned short* Al0 = &As[w * 512];
    unsigned short* Al1 = &As[(w + 4) * 512];
    unsigned short* Bl0 = &Bs[w * 512];
    unsigned short* Bl1 = &Bs[(w + 4) * 512];

    floatx4 acc[4][4];
#pragma unroll
    for (int mt = 0; mt < 4; mt++)
#pragma unroll
        for (int nt = 0; nt < 4; nt++) acc[mt][nt] = (floatx4){0.f, 0.f, 0.f, 0.f};

    for (int k0 = 0; k0 < K; k0 += 32) {
        __syncthreads();
        gl_lds16(Ag0 + k0, Al0);
        gl_lds16(Ag1 + k0, Al1);
        gl_lds16(Bg0 + k0, Bl0);
        gl_lds16(Bg1 + k0, Bl1);
        __syncthreads();
        bf16x8 fa[4], fb[4];
#pragma unroll
        for (int mt = 0; mt < 4; mt++) fa[mt] = *(const bf16x8*)&As[(wm * 64 + mt * 16 + qi) * 32 + g * 8];
#pragma unroll
        for (int nt = 0; nt < 4; nt++) fb[nt] = *(const bf16x8*)&Bs[(wn * 64 + nt * 16 + qi) * 32 + g * 8];
#pragma unroll
        for (int mt = 0; mt < 4; mt++)
#pragma unroll
            for (int nt = 0; nt < 4; nt++)
                acc[mt][nt] = __builtin_amdgcn_mfma_f32_16x16x32_bf16(fa[mt], fb[nt], acc[mt][nt], 0, 0, 0);
    }
#pragma unroll
    for (int mt = 0; mt < 4; mt++)
#pragma unroll
        for (int nt = 0; nt < 4; nt++)
#pragma unroll
            for (int r = 0; r < 4; r++) {
                long row = gm + wm * 64 + mt * 16 + g * 4 + r;
                long col = gn + wn * 64 + nt * 16 + qi;
                float v = acc[mt][nt][r];
                if (obf) ((unsigned short*)C)[row * N + col] = f2bf(v);
                else     ((float*)C)[row * N + col] = v;
            }
}

// ---- flash attention v4: work-balanced pairing.
// Block j handles q-chunk j (2j+2 key tiles) AND q-chunk 15-j (32-2j tiles):
// 34 tiles for EVERY block -> balanced no matter how blocks map to CUs.
// (R4 lesson: grid stride 256 ≡ 0 mod 16 put equal-qblk blocks on one CU.)
// Within a chunk: 4 waves x 32 q rows, 64-key LDS tiles, kk-outer QK,
// one batched softmax round per q-tile, fv shared across q-tiles in PV.
__global__ __launch_bounds__(256) void k_attn(const unsigned short* q, const unsigned short* kv,
                                              const unsigned short* krot, const unsigned short* vt,
                                              unsigned short* out) {
    __shared__ __align__(16) unsigned short Ks[64 * 96];  // key-major, 64+32 fused, stride 96
    __shared__ __align__(16) unsigned short Vs[64 * 80];  // vd-major V^T, stride 80
    int tid = threadIdx.x;
    int lane = tid & 63, w = tid >> 6;
    int b = blockIdx.z, h = blockIdx.y;
    int j = blockIdx.x;                      // 0..7
    int g = lane >> 4, qi = lane & 15;
    long tok0 = (long)b * S_;

    const unsigned short* kbase = kv + tok0 * HKV + h * 128;
    const unsigned short* krb   = krot + tok0 * ROPE_;
    const unsigned short* vtb   = vt + ((long)(b * H_ + h) * 64) * S_;

    for (int half = 0; half < 2; half++) {
        int qblk = half ? (15 - j) : j;
        int qbase = qblk * 128;

        bf16x8 fq[2][3];
#pragma unroll
        for (int qt = 0; qt < 2; qt++) {
            const unsigned short* qp = q + (tok0 + qbase + w * 32 + qt * 16 + qi) * HQKD + h * QKD_;
#pragma unroll
            for (int c = 0; c < 3; c++) fq[qt][c] = *(const bf16x8*)&qp[c * 32 + g * 8];
        }

        floatx4 o[2][4];
#pragma unroll
        for (int qt = 0; qt < 2; qt++)
#pragma unroll
            for (int vc = 0; vc < 4; vc++) o[qt][vc] = (floatx4){0.f, 0.f, 0.f, 0.f};
        float m[2] = {-1e30f, -1e30f}, l[2] = {0.f, 0.f};

        int ktb = 2 * qblk + 2;
        int ktmax_w = (qbase + w * 32 + 31) >> 6;

        for (int kt = 0; kt < ktb; kt++) {
            int k0 = kt * 64;
            __syncthreads();
            // stage K (pass cols 0..63 from kv, rope cols 64..95 from krot)
#pragma unroll
            for (int i = 0; i < 3; i++) {
                int idx = tid + i * 256;
                int row = idx / 12, c = (idx % 12) * 8;
                const unsigned short* src = (c < 64)
                    ? kbase + (long)(k0 + row) * HKV + c
                    : krb + (long)(k0 + row) * ROPE_ + (c - 64);
                *(ushort8_t*)&Ks[row * 96 + c] = *(const ushort8_t*)src;
            }
            // stage V^T
#pragma unroll
            for (int i = 0; i < 2; i++) {
                int idx = tid + i * 256;
                int row = idx >> 3, c = (idx & 7) * 8;
                *(ushort8_t*)&Vs[row * 80 + c] = *(const ushort8_t*)&vtb[(long)row * S_ + k0 + c];
            }
            __syncthreads();
            if (kt > ktmax_w) continue;   // stage-only past this wave's causal limit

            // ---- QK^T: kk-outer so each K fragment is read once
            floatx4 st[2][4];
#pragma unroll
            for (int kk = 0; kk < 4; kk++) {
                const unsigned short* kr = &Ks[(kk * 16 + qi) * 96];
                bf16x8 fk0 = *(const bf16x8*)&kr[g * 8];
                bf16x8 fk1 = *(const bf16x8*)&kr[32 + g * 8];
                bf16x8 fk2 = *(const bf16x8*)&kr[64 + g * 8];
#pragma unroll
                for (int qt = 0; qt < 2; qt++) {
                    floatx4 s = (floatx4){0.f, 0.f, 0.f, 0.f};
                    s = __builtin_amdgcn_mfma_f32_16x16x32_bf16(fk0, fq[qt][0], s, 0, 0, 0);
                    s = __builtin_amdgcn_mfma_f32_16x16x32_bf16(fk1, fq[qt][1], s, 0, 0, 0);
                    s = __builtin_amdgcn_mfma_f32_16x16x32_bf16(fk2, fq[qt][2], s, 0, 0, 0);
                    st[qt][kk] = s;
                }
            }

            // ---- batched online softmax: one reduction round per q-tile per 64 keys
            shortx4 fp[2][4];
#pragma unroll
            for (int qt = 0; qt < 2; qt++) {
                int qrow = qbase + w * 32 + qt * 16 + qi;
                // mask needed iff max_key (k0+63) exceeds the SMALLEST q-row of the tile
                bool need_mask = (k0 + 63) > (qbase + w * 32 + qt * 16);  // wave-uniform
                float sv[4][4];
                float tmax = -3e30f;
#pragma unroll
                for (int kk = 0; kk < 4; kk++)
#pragma unroll
                    for (int r = 0; r < 4; r++) {
                        float s = st[qt][kk][r] * SCALING_;
                        if (need_mask && (k0 + kk * 16 + g * 4 + r) > qrow) s = -1e30f;
                        sv[kk][r] = s;
                        tmax = fmaxf(tmax, s);
                    }
                tmax = fmaxf(tmax, __shfl_xor(tmax, 16, 64));
                tmax = fmaxf(tmax, __shfl_xor(tmax, 32, 64));
                float mnew = fmaxf(m[qt], tmax);
                float alpha = __expf(m[qt] - mnew);
                float ps = 0.f;
#pragma unroll
                for (int kk = 0; kk < 4; kk++)
#pragma unroll
                    for (int r = 0; r < 4; r++) {
                        float p = __expf(sv[kk][r] - mnew);
                        ps += p;
                        fp[qt][kk][r] = (short)f2bf(p);
                    }
                ps += __shfl_xor(ps, 16, 64);
                ps += __shfl_xor(ps, 32, 64);
                l[qt] = l[qt] * alpha + ps;
                m[qt] = mnew;
                float ar[4];
#pragma unroll
                for (int r = 0; r < 4; r++) ar[r] = __shfl(alpha, (lane & 48) | (g * 4 + r), 64);
#pragma unroll
                for (int vc = 0; vc < 4; vc++) {
                    o[qt][vc][0] *= ar[0]; o[qt][vc][1] *= ar[1];
                    o[qt][vc][2] *= ar[2]; o[qt][vc][3] *= ar[3];
                }
            }

            // ---- PV: fv loaded once per kk, shared by both q-tiles
#pragma unroll
            for (int kk = 0; kk < 4; kk++) {
                shortx4 fv[4];
#pragma unroll
                for (int vc = 0; vc < 4; vc++)
                    fv[vc] = *(const shortx4*)&Vs[(vc * 16 + qi) * 80 + kk * 16 + g * 4];
#pragma unroll
                for (int qt = 0; qt < 2; qt++)
#pragma unroll
                    for (int vc = 0; vc < 4; vc++)
                        o[qt][vc] = __builtin_amdgcn_mfma_f32_16x16x16bf16_1k(fp[qt][kk], fv[vc], o[qt][vc], 0, 0, 0);
            }
        }

#pragma unroll
        for (int qt = 0; qt < 2; qt++) {
            float lr[4];
#pragma unroll
            for (int r = 0; r < 4; r++) lr[r] = __shfl(l[qt], (lane & 48) | (g * 4 + r), 64);
#pragma unroll
            for (int vc = 0; vc < 4; vc++)
#pragma unroll
                for (int r = 0; r < 4; r++)
                    out[(tok0 + qbase + w * 32 + qt * 16 + g * 4 + r) * HVD + h * VD_ + vc * 16 + qi] =
                        f2bf(o[qt][vc][r] / lr[r]);
        }
    }
}

extern "C" void kernel_launch(void* const* d_in, const int* in_sizes, int n_in,
                              void* d_out, int out_size, void* d_ws, size_t ws_size,
                              hipStream_t stream) {
    const void* hidden = d_in[0];
    const void* cosb   = d_in[1];
    const void* sinb   = d_in[2];
    const void* wq_a   = d_in[3];
    const void* q_ln   = d_in[4];
    const void* wq_b   = d_in[5];
    const void* wkv_a  = d_in[6];
    const void* kv_ln  = d_in[7];
    const void* wkv_b  = d_in[8];
    const void* wo     = d_in[9];

    char* ws = (char*)d_ws;
    size_t off = 0;
    auto alloc = [&](size_t bytes) -> void* {
        void* p = ws + off;
        off += (bytes + 255) & ~(size_t)255;
        return p;
    };
    int* flag                = (int*)alloc(256);
    unsigned short* hbf      = (unsigned short*)alloc((size_t)TOK * HID_ * 2);  // reused as vt later
    unsigned short* wqa_t    = (unsigned short*)alloc((size_t)QRANK_ * HID_ * 2);
    unsigned short* wqb_t    = (unsigned short*)alloc((size_t)HQKD * QRANK_ * 2);
    unsigned short* wkva_t   = (unsigned short*)alloc((size_t)KVRP_PAD * HID_ * 2);
    unsigned short* wkvb_t   = (unsigned short*)alloc((size_t)HKV * KVRANK_ * 2);
    unsigned short* wo_t     = (unsigned short*)alloc((size_t)HID_ * HVD * 2);
    float*          q_a      = (float*)alloc((size_t)TOK * QRANK_ * 4);
    unsigned short* q_a_n    = (unsigned short*)alloc((size_t)TOK * QRANK_ * 2);
    unsigned short* q_raw    = (unsigned short*)alloc((size_t)TOK * HQKD * 2);
    float*          ckv      = (float*)alloc((size_t)TOK * KVRP_PAD * 4);
    unsigned short* kc_n     = (unsigned short*)alloc((size_t)TOK * KVRANK_ * 2);
    unsigned short* kv_raw   = (unsigned short*)alloc((size_t)TOK * HKV * 2);
    unsigned short* krot     = (unsigned short*)alloc((size_t)TOK * ROPE_ * 2);
    unsigned short* attn_o   = (unsigned short*)alloc((size_t)TOK * HVD * 2);
    unsigned short* vt       = hbf;  // hbf dead after the two A-gemms; same elem count

    k_detect<<<1, 64, 0, stream>>>((const unsigned short*)cosb, flag);

    long nh = (long)TOK * HID_;
    k_tobf<<<(int)((nh + 255) / 256), 256, 0, stream>>>(hidden, hbf, nh, flag);

    k_transpose<<<dim3(HID_ / 32, QRANK_ / 32), 256, 0, stream>>>(wq_a, wqa_t, HID_, QRANK_, QRANK_, flag);
    k_transpose<<<dim3(QRANK_ / 32, HQKD / 32), 256, 0, stream>>>(wq_b, wqb_t, QRANK_, HQKD, HQKD, flag);
    k_transpose<<<dim3(HID_ / 32, KVRP_PAD / 32), 256, 0, stream>>>(wkv_a, wkva_t, HID_, KVRP_, KVRP_PAD, flag);
    k_transpose<<<dim3(KVRANK_ / 32, HKV / 32), 256, 0, stream>>>(wkv_b, wkvb_t, KVRANK_, HKV, HKV, flag);
    k_transpose<<<dim3(HVD / 32, HID_ / 32), 256, 0, stream>>>(wo, wo_t, HVD, HID_, HID_, flag);

    // q chain
    k_gemm<<<dim3(QRANK_ / 128, TOK / 128), 256, 0, stream>>>(hbf, wqa_t, q_a, TOK, QRANK_, HID_, 0, flag);
    k_rmsnorm<<<TOK, 256, 0, stream>>>(q_a, QRANK_, QRANK_, q_ln, q_a_n, QRANK_, flag);
    k_gemm<<<dim3(HQKD / 128, TOK / 128), 256, 0, stream>>>(q_a_n, wqb_t, q_raw, TOK, HQKD, QRANK_, 1, flag);

    // kv chain
    k_gemm<<<dim3(KVRP_PAD / 128, TOK / 128), 256, 0, stream>>>(hbf, wkva_t, ckv, TOK, KVRP_PAD, HID_, 0, flag);
    k_rmsnorm<<<TOK, 256, 0, stream>>>(ckv, KVRP_PAD, KVRANK_, kv_ln, kc_n, KVRANK_, flag);
    k_gemm<<<dim3(HKV / 128, TOK / 128), 256, 0, stream>>>(kc_n, wkvb_t, kv_raw, TOK, HKV, KVRANK_, 1, flag);

    // rope
    long nrq = (long)TOK * H_ * 16;
    k_rope_q<<<(int)((nrq + 255) / 256), 256, 0, stream>>>(q_raw, cosb, sinb, flag);
    long nrk = (long)TOK * 16;
    k_rope_k<<<(int)((nrk + 255) / 256), 256, 0, stream>>>(ckv, krot, cosb, sinb, flag);

    // V transpose (into dead hbf buffer), then attention (balanced pairing: S_/256 pairs)
    k_vtrans<<<dim3(S_ / 32, VD_ / 32, B_ * H_), 256, 0, stream>>>(kv_raw, vt);
    k_attn<<<dim3(S_ / 256, H_, B_), 256, 0, stream>>>(q_raw, kv_raw, krot, vt, attn_o);

    // output projection (dtype per detected mode)
    k_gemm<<<dim3(HID_ / 128, TOK / 128), 256, 0, stream>>>(attn_o, wo_t, d_out, TOK, HID_, HVD, 2, flag);
}